// Round 5
// baseline (1724.331 us; speedup 1.0000x reference)
//
#include <hip/hip_runtime.h>
#include <cstdint>
#include <cstdio>

#define DIMF 128

typedef __attribute__((ext_vector_type(8))) short short8v;
typedef __attribute__((ext_vector_type(4))) float f32x4;

// Feature format: each row = 128 u32 words; word j = hi_bf16(x_j) | lo_bf16 << 16
// where x ~= hi + lo (split-bf16, ~2^-17 rel err).

// ---------------- JAX threefry2x32 (exact) ----------------
__host__ __device__ __forceinline__ void tf2x32(uint32_t k0, uint32_t k1,
                                                uint32_t x0, uint32_t x1,
                                                uint32_t& o0, uint32_t& o1) {
  uint32_t ks2 = k0 ^ k1 ^ 0x1BD11BDAu;
  x0 += k0; x1 += k1;
#define TFR(r) { x0 += x1; x1 = (x1 << (r)) | (x1 >> (32 - (r))); x1 ^= x0; }
  TFR(13) TFR(15) TFR(26) TFR(6)
  x0 += k1;  x1 += ks2 + 1u;
  TFR(17) TFR(29) TFR(16) TFR(24)
  x0 += ks2; x1 += k0 + 2u;
  TFR(13) TFR(15) TFR(26) TFR(6)
  x0 += k0;  x1 += k1 + 3u;
  TFR(17) TFR(29) TFR(16) TFR(24)
  x0 += k1;  x1 += ks2 + 4u;
  TFR(13) TFR(15) TFR(26) TFR(6)
  x0 += ks2; x1 += k0 + 5u;
#undef TFR
  o0 = x0; o1 = x1;
}

__device__ __forceinline__ short f2bf_rne(float x) {
  uint32_t u = __float_as_uint(x);
  uint32_t r = (u + 0x7FFFu + ((u >> 16) & 1u)) >> 16;
  return (short)r;
}
__device__ __forceinline__ float bfhi_f(short h) {
  return __uint_as_float(((uint32_t)(uint16_t)h) << 16);
}
__device__ __forceinline__ uint32_t pack_hl(float v) {
  short hi = f2bf_rne(v);
  short lo = f2bf_rne(v - bfhi_f(hi));
  return (uint32_t)(uint16_t)hi | ((uint32_t)(uint16_t)lo << 16);
}
__device__ __forceinline__ float unpk_sum(uint32_t w) {
  return __uint_as_float(w << 16) + __uint_as_float(w & 0xFFFF0000u);
}
__device__ __forceinline__ void pack2(uint32_t we, uint32_t wo, uint32_t& h, uint32_t& l) {
  h = (we & 0xFFFFu) | (wo << 16);
  l = (we >> 16) | (wo & 0xFFFF0000u);
}

// ---------------- input dropout(0.2)+relu -> interleaved rows ----------------
__global__ __launch_bounds__(256) void k_drop_in(const float* __restrict__ in,
                                                 uint32_t* __restrict__ out,
                                                 int npair, uint32_t k0, uint32_t k1) {
  int p = blockIdx.x * 256 + threadIdx.x;
  if (p >= npair) return;
  int row = p >> 6, c2 = (p & 63) * 2;
  float2 x = *(const float2*)(in + (size_t)row * 128 + c2);
  uint32_t idx = (uint32_t)(row * 128 + c2);
  float v[2] = {x.x, x.y};
  uint32_t wv[2];
#pragma unroll
  for (int q = 0; q < 2; ++q) {
    uint32_t o0, o1;
    tf2x32(k0, k1, 0u, idx + q, o0, o1);
    uint32_t bits = o0 ^ o1;
    float u = __uint_as_float((bits >> 9) | 0x3f800000u) - 1.0f;
    float y = (u < 0.8f) ? (v[q] / 0.8f) : 0.0f;
    y = fmaxf(y, 0.0f);
    wv[q] = pack_hl(y);
  }
  *(uint2*)(out + (size_t)row * 128 + c2) = make_uint2(wv[0], wv[1]);
}

// ---------------- CSR build (merged over 3 edge types) ----------------
__global__ __launch_bounds__(256) void k_count3(const int* __restrict__ ei0,
                                                const int* __restrict__ ei1,
                                                const int* __restrict__ ei2,
                                                int* __restrict__ cnt, int E, int n, int gE) {
  int b = blockIdx.x;
  int type = b / gE;
  int e = (b - type * gE) * 256 + threadIdx.x;
  if (e >= E) return;
  const int* ei = type == 0 ? ei0 : (type == 1 ? ei1 : ei2);
  atomicAdd(cnt + type * n + ei[E + e], 1);
}

__global__ __launch_bounds__(256) void k_scanA(const int* __restrict__ cnt,
                                               int* __restrict__ off,
                                               int* __restrict__ bsum, int n3) {
  __shared__ int ts[256];
  int t = threadIdx.x;
  int base = blockIdx.x * 1024 + t * 4;
  int v[4];
#pragma unroll
  for (int i = 0; i < 4; ++i) v[i] = (base + i < n3) ? cnt[base + i] : 0;
  ts[t] = v[0] + v[1] + v[2] + v[3];
  __syncthreads();
  for (int ofs = 1; ofs < 256; ofs <<= 1) {
    int x = ts[t];
    int y = (t >= ofs) ? ts[t - ofs] : 0;
    __syncthreads();
    ts[t] = x + y;
    __syncthreads();
  }
  int run = (t == 0) ? 0 : ts[t - 1];
  if (t == 255) bsum[blockIdx.x] = ts[255];
#pragma unroll
  for (int i = 0; i < 4; ++i) {
    if (base + i < n3) off[base + i] = run;
    run += v[i];
  }
}

__global__ __launch_bounds__(256) void k_scanB(int* __restrict__ bsum, int nb,
                                               int* __restrict__ off, int n3) {
  __shared__ int ts[256];
  int t = threadIdx.x;
  int base = t * 4;
  int v[4];
#pragma unroll
  for (int i = 0; i < 4; ++i) v[i] = (base + i < nb) ? bsum[base + i] : 0;
  ts[t] = v[0] + v[1] + v[2] + v[3];
  __syncthreads();
  for (int ofs = 1; ofs < 256; ofs <<= 1) {
    int x = ts[t];
    int y = (t >= ofs) ? ts[t - ofs] : 0;
    __syncthreads();
    ts[t] = x + y;
    __syncthreads();
  }
  int run = (t == 0) ? 0 : ts[t - 1];
  if (t == 255) off[n3] = ts[255];
#pragma unroll
  for (int i = 0; i < 4; ++i) {
    if (base + i < nb) bsum[base + i] = run;
    run += v[i];
  }
}

__global__ __launch_bounds__(256) void k_scanC(int* __restrict__ off,
                                               const int* __restrict__ bsum,
                                               int* __restrict__ cur, int n3) {
  int i = blockIdx.x * 256 + threadIdx.x;
  if (i < n3) {
    int o = off[i] + bsum[i >> 10];
    off[i] = o;
    cur[i] = o;
  }
}

__global__ __launch_bounds__(256) void k_fill3(const int* __restrict__ ei0,
                                               const int* __restrict__ ei1,
                                               const int* __restrict__ ei2,
                                               int* __restrict__ cur,
                                               int* __restrict__ srcl, int E, int n, int gE) {
  int b = blockIdx.x;
  int type = b / gE;
  int e = (b - type * gE) * 256 + threadIdx.x;
  if (e >= E) return;
  const int* ei = type == 0 ? ei0 : (type == 1 ? ei1 : ei2);
  int pos = atomicAdd(cur + type * n + ei[E + e], 1);
  srcl[pos] = ei[e];
}

// ---------------- CSR gather-mean (interleaved in/out), 2 sets per dispatch ----------------
__device__ __forceinline__ void gather_one(const uint32_t* __restrict__ feat,
                                           const int* __restrict__ off,
                                           const int* __restrict__ srcl,
                                           uint32_t* __restrict__ out,
                                           int d, int lane) {
  int b = off[d], e = off[d + 1];
  float a0 = 0.f, a1 = 0.f, b0 = 0.f, b1 = 0.f;
  float c0 = 0.f, c1 = 0.f, d0 = 0.f, d1 = 0.f;
  const int c2 = lane * 2;
  int j = b;
  for (; j + 3 < e; j += 4) {
    int s0 = srcl[j], s1 = srcl[j + 1], s2 = srcl[j + 2], s3 = srcl[j + 3];
    uint2 w0 = *(const uint2*)(feat + (size_t)s0 * 128 + c2);
    uint2 w1 = *(const uint2*)(feat + (size_t)s1 * 128 + c2);
    uint2 w2 = *(const uint2*)(feat + (size_t)s2 * 128 + c2);
    uint2 w3 = *(const uint2*)(feat + (size_t)s3 * 128 + c2);
    a0 += unpk_sum(w0.x); a1 += unpk_sum(w0.y);
    b0 += unpk_sum(w1.x); b1 += unpk_sum(w1.y);
    c0 += unpk_sum(w2.x); c1 += unpk_sum(w2.y);
    d0 += unpk_sum(w3.x); d1 += unpk_sum(w3.y);
  }
  for (; j < e; ++j) {
    int s = srcl[j];
    uint2 w = *(const uint2*)(feat + (size_t)s * 128 + c2);
    a0 += unpk_sum(w.x); a1 += unpk_sum(w.y);
  }
  float sc = 1.0f / (float)max(e - b, 1);
  float v0 = ((a0 + b0) + (c0 + d0)) * sc;
  float v1 = ((a1 + b1) + (c1 + d1)) * sc;
  *(uint2*)(out + (size_t)d * 128 + c2) = make_uint2(pack_hl(v0), pack_hl(v1));
}

__global__ __launch_bounds__(256) void k_gather2(
    const uint32_t* __restrict__ fX, const int* __restrict__ offX, uint32_t* __restrict__ oX,
    const uint32_t* __restrict__ fY, const int* __restrict__ offY, uint32_t* __restrict__ oY,
    const int* __restrict__ srcl, int n) {
  int wid = (blockIdx.x * 256 + threadIdx.x) >> 6;
  int lane = threadIdx.x & 63;
  if (wid >= 2 * n) return;
  if (wid < n) gather_one(fX, offX, srcl, oX, wid, lane);
  else         gather_one(fY, offY, srcl, oY, wid - n, lane);
}

__global__ __launch_bounds__(256) void k_gather1(
    const uint32_t* __restrict__ f, const int* __restrict__ off, uint32_t* __restrict__ o,
    const int* __restrict__ srcl, int n) {
  int wid = (blockIdx.x * 256 + threadIdx.x) >> 6;
  int lane = threadIdx.x & 63;
  if (wid >= n) return;
  gather_one(f, off, srcl, o, wid, lane);
}

// ---------------- combined-weight precompute: C=A0@B0(+A1@B1) -> transposed hi/lo planar ----------------
struct WDesc { const float* A0; const float* B0; const float* A1; const float* B1; short* Ch; short* Cl; };
struct WPack { WDesc d[10]; };

__global__ __launch_bounds__(256) void k_wprec(WPack p) {
  const WDesc d = p.d[blockIdx.x >> 2];
  const int rt = blockIdx.x & 3;
  __shared__ float A_s[32 * 128];
  const int t = threadIdx.x;
  const int c = t & 127, rh = t >> 7;
  float acc[16];
#pragma unroll
  for (int i = 0; i < 16; ++i) acc[i] = 0.f;
  for (int pass = 0; pass < 2; ++pass) {
    const float* A = pass ? d.A1 : d.A0;
    const float* B = pass ? d.B1 : d.B0;
    if (!A) break;
    __syncthreads();
#pragma unroll
    for (int j = 0; j < 4; ++j) {
      int f = t + 256 * j;
      *(float4*)(A_s + 4 * f) = *(const float4*)(A + (size_t)rt * 32 * 128 + 4 * f);
    }
    __syncthreads();
    for (int k = 0; k < 128; ++k) {
      float b = B[(size_t)k * 128 + c];
#pragma unroll
      for (int i = 0; i < 16; ++i)
        acc[i] += A_s[(rh + 2 * i) * 128 + k] * b;
    }
  }
#pragma unroll
  for (int i = 0; i < 16; ++i) {
    int k = rt * 32 + rh + 2 * i;
    float v = acc[i];
    short hi = f2bf_rne(v);
    short lo = f2bf_rne(v - bfhi_f(hi));
    d.Ch[(size_t)c * 128 + k] = hi;
    d.Cl[(size_t)c * 128 + k] = lo;
  }
}

// ---------------- combined bias ----------------
__global__ __launch_bounds__(256) void k_bias(const float* __restrict__ bn,
                                              const float* __restrict__ bs,
                                              const float* __restrict__ bu,
                                              const float* __restrict__ Wu,
                                              float* __restrict__ cbA, float* __restrict__ cbB) {
  int t = threadIdx.x;
  int h = t & 127;
  if (t < 128) {
    float acc = bu[0 * 128 + h] + bu[2 * 128 + h];
    for (int j = 0; j < 128; ++j) {
      acc += bn[0 * 128 + j] * Wu[(size_t)0 * 32768 + (size_t)j * 128 + h];
      acc += bs[0 * 128 + j] * Wu[(size_t)0 * 32768 + 16384 + (size_t)j * 128 + h];
      acc += bn[2 * 128 + j] * Wu[(size_t)2 * 32768 + (size_t)j * 128 + h];
      acc += bs[2 * 128 + j] * Wu[(size_t)2 * 32768 + 16384 + (size_t)j * 128 + h];
    }
    cbA[h] = acc;
  } else {
    float acc = bu[128 + h];
    for (int j = 0; j < 128; ++j) {
      acc += bn[128 + j] * Wu[(size_t)1 * 32768 + (size_t)j * 128 + h];
      acc += bs[128 + j] * Wu[(size_t)1 * 32768 + 16384 + (size_t)j * 128 + h];
    }
    cbB[h] = acc;
  }
}

// ---------------- split-bf16 MFMA multi-term matmul (interleaved features) ----------------
template <int NT, int MODE>
__global__ __launch_bounds__(256, 2) void k_mmx(
    const uint32_t* __restrict__ s0, const uint32_t* __restrict__ s1, const uint32_t* __restrict__ s2,
    const short* __restrict__ w0h, const short* __restrict__ w0l,
    const short* __restrict__ w1h, const short* __restrict__ w1l,
    const short* __restrict__ w2h, const short* __restrict__ w2l,
    const float* __restrict__ bias, void* __restrict__ outv, int n,
    uint32_t k0, uint32_t k1) {
  __shared__ short A_s[128 * 72];   // [row][32hi|32lo|8pad] shorts, 144B stride
  __shared__ short W_s[128 * 72];   // [n][32hi|32lo|8pad]
  const int t = threadIdx.x;
  const int r0 = blockIdx.x * 128;
  const int lane = t & 63;
  const int w = t >> 6;
  const int wr = w >> 1, wc = w & 1;
  const int lr = lane & 15, lg = lane >> 4;
  const int sr = t >> 1, sh = t & 1;

  f32x4 acc[4][4];
#pragma unroll
  for (int nf = 0; nf < 4; ++nf) {
    float bv = bias[wc * 64 + nf * 16 + lr];
#pragma unroll
    for (int mf = 0; mf < 4; ++mf) acc[mf][nf] = {bv, bv, bv, bv};
  }

  for (int term = 0; term < NT; ++term) {
    const uint32_t* src = term == 0 ? s0 : (term == 1 ? s1 : s2);
    const short* wh  = term == 0 ? w0h : (term == 1 ? w1h : w2h);
    const short* wl  = term == 0 ? w0l : (term == 1 ? w1l : w2l);
    const short* wsrc = sh ? wl : wh;
    for (int ks = 0; ks < 4; ++ks) {
      __syncthreads();
      { // A tile: 16 interleaved words -> 16 hi + 16 lo shorts (planar)
        const uint4* ga = (const uint4*)(src + (size_t)(r0 + sr) * 128 + ks * 32 + sh * 16);
        uint4 q0 = ga[0], q1 = ga[1], q2 = ga[2], q3 = ga[3];
        uint32_t h[8], l[8];
        pack2(q0.x, q0.y, h[0], l[0]); pack2(q0.z, q0.w, h[1], l[1]);
        pack2(q1.x, q1.y, h[2], l[2]); pack2(q1.z, q1.w, h[3], l[3]);
        pack2(q2.x, q2.y, h[4], l[4]); pack2(q2.z, q2.w, h[5], l[5]);
        pack2(q3.x, q3.y, h[6], l[6]); pack2(q3.z, q3.w, h[7], l[7]);
        uint4* Ah = (uint4*)(A_s + sr * 72 + sh * 16);
        uint4* Al = (uint4*)(A_s + sr * 72 + 32 + sh * 16);
        Ah[0] = make_uint4(h[0], h[1], h[2], h[3]);
        Ah[1] = make_uint4(h[4], h[5], h[6], h[7]);
        Al[0] = make_uint4(l[0], l[1], l[2], l[3]);
        Al[1] = make_uint4(l[4], l[5], l[6], l[7]);
        // W tile (planar source)
        const uint4* gw = (const uint4*)(wsrc + sr * 128 + ks * 32);
        uint4 b0 = gw[0], b1 = gw[1], b2 = gw[2], b3 = gw[3];
        uint4* lw = (uint4*)(W_s + sr * 72 + sh * 32);
        lw[0] = b0; lw[1] = b1; lw[2] = b2; lw[3] = b3;
      }
      __syncthreads();
      short8v whi[4], wlo[4];
#pragma unroll
      for (int nf = 0; nf < 4; ++nf) {
        int nc = wc * 64 + nf * 16 + lr;
        whi[nf] = *(const short8v*)(W_s + nc * 72 + lg * 8);
        wlo[nf] = *(const short8v*)(W_s + nc * 72 + 32 + lg * 8);
      }
#pragma unroll
      for (int mf = 0; mf < 4; ++mf) {
        int ar = wr * 64 + mf * 16 + lr;
        short8v ah = *(const short8v*)(A_s + ar * 72 + lg * 8);
        short8v al = *(const short8v*)(A_s + ar * 72 + 32 + lg * 8);
#pragma unroll
        for (int nf = 0; nf < 4; ++nf) {
          acc[mf][nf] = __builtin_amdgcn_mfma_f32_16x16x32_bf16(ah, whi[nf], acc[mf][nf], 0, 0, 0);
          acc[mf][nf] = __builtin_amdgcn_mfma_f32_16x16x32_bf16(ah, wlo[nf], acc[mf][nf], 0, 0, 0);
          acc[mf][nf] = __builtin_amdgcn_mfma_f32_16x16x32_bf16(al, whi[nf], acc[mf][nf], 0, 0, 0);
        }
      }
    }
  }

#pragma unroll
  for (int mf = 0; mf < 4; ++mf) {
#pragma unroll
    for (int r = 0; r < 4; ++r) {
      int g = r0 + wr * 64 + mf * 16 + lg * 4 + r;
      if (g >= n) continue;
#pragma unroll
      for (int nf = 0; nf < 4; ++nf) {
        int col = wc * 64 + nf * 16 + lr;
        float v = acc[mf][nf][r];
        if constexpr (MODE == 1) {
          uint32_t o0, o1;
          tf2x32(k0, k1, 0u, (uint32_t)(g * 128 + col), o0, o1);
          uint32_t bits = o0 ^ o1;
          float u = __uint_as_float((bits >> 9) | 0x3f800000u) - 1.0f;
          v = (u < 0.8f) ? (v / 0.8f) : 0.0f;
          v = fmaxf(v, 0.0f);
          ((uint32_t*)outv)[(size_t)g * 128 + col] = pack_hl(v);
        } else {
          ((float*)outv)[(size_t)g * 128 + col] = v;
        }
      }
    }
  }
}

// ---------------- host driver ----------------
extern "C" void kernel_launch(void* const* d_in, const int* in_sizes, int n_in,
                              void* d_out, int out_size, void* d_ws, size_t ws_size,
                              hipStream_t stream) {
  const float* xA  = (const float*)d_in[0];
  const float* xB  = (const float*)d_in[1];
  const int*   ei0 = (const int*)d_in[2];
  const int*   ei1 = (const int*)d_in[3];
  const int*   ei2 = (const int*)d_in[4];
  const float* Wn1 = (const float*)d_in[5];
  const float* Ws1 = (const float*)d_in[6];
  const float* Wu1 = (const float*)d_in[7];
  const float* Wn2 = (const float*)d_in[8];
  const float* Ws2 = (const float*)d_in[9];
  const float* Wu2 = (const float*)d_in[10];
  const float* bn1 = (const float*)d_in[11];
  const float* bs1 = (const float*)d_in[12];
  const float* bu1 = (const float*)d_in[13];
  const float* bn2 = (const float*)d_in[14];
  const float* bs2 = (const float*)d_in[15];
  const float* bu2 = (const float*)d_in[16];

  const int n  = in_sizes[0] / DIMF;        // 100000
  const int E  = in_sizes[2] / 2;           // 1600000
  const int n3 = 3 * n;
  const size_t nh = (size_t)n * DIMF;

  float* ws = (float*)d_ws;
  uint32_t* buf_hA = (uint32_t*)(ws);           // hA -> h2A (in place)
  uint32_t* buf_hB = (uint32_t*)(ws + nh);      // hB -> h2B (in place)
  uint32_t* g1     = (uint32_t*)(ws + 2 * nh);  // gather scratch (ei1 / ei0)
  uint32_t* g2     = (uint32_t*)(ws + 3 * nh);  // gather scratch (ei2)
  short* wtsS   = (short*)(ws + 4 * nh);        // 10 x (16384 hi + 16384 lo) shorts
  float* biasF  = (float*)(wtsS + 10 * 32768);
  float* cbA1 = biasF, *cbB1 = biasF + 128, *cbA2 = biasF + 256, *cbB2 = biasF + 384;
  int* cnt  = (int*)(biasF + 512);          // [3n]
  int* off  = cnt + n3;                     // [3n+1]
  int* cur  = off + n3 + 1;                 // [3n]
  int* bsum = cur + n3;                     // [1024]
  int* srcl = bsum + 1024;                  // [3E]

  size_t need_bytes = (4 * nh + 512) * sizeof(float)
                    + (size_t)10 * 32768 * sizeof(short)
                    + ((size_t)3 * n3 + 1 + 1024 + (size_t)3 * E) * sizeof(int)
                    + 65536;
  if (ws_size < need_bytes) {
    fprintf(stderr, "kernel_launch: ws too small (%zu < %zu)\n", ws_size, need_bytes);
    return;
  }

  // JAX keys: dk = split(key(42), 4) (partitionable threefry, verified round 2)
  uint32_t dk[4][2];
  for (uint32_t i = 0; i < 4; ++i) tf2x32(0u, 42u, 0u, i, dk[i][0], dk[i][1]);

  WPack pk;
  auto U = [](const float* Wu, int t) { return Wu + (size_t)t * 32768; };
  auto L = [](const float* Wu, int t) { return Wu + (size_t)t * 32768 + 16384; };
  auto WH = [&](int m) { return wtsS + (size_t)m * 32768; };
  auto WL = [&](int m) { return wtsS + (size_t)m * 32768 + 16384; };
  const size_t MS = 128 * 128;
  pk.d[0] = { Wn1 + 0 * MS, U(Wu1, 0), nullptr, nullptr, WH(0), WL(0) };
  pk.d[1] = { Wn1 + 1 * MS, U(Wu1, 1), nullptr, nullptr, WH(1), WL(1) };
  pk.d[2] = { Wn1 + 2 * MS, U(Wu1, 2), nullptr, nullptr, WH(2), WL(2) };
  pk.d[3] = { Ws1 + 0 * MS, L(Wu1, 0), Ws1 + 2 * MS, L(Wu1, 2), WH(3), WL(3) };
  pk.d[4] = { Ws1 + 1 * MS, L(Wu1, 1), nullptr, nullptr, WH(4), WL(4) };
  pk.d[5] = { Wn2 + 0 * MS, U(Wu2, 0), nullptr, nullptr, WH(5), WL(5) };
  pk.d[6] = { Wn2 + 1 * MS, U(Wu2, 1), nullptr, nullptr, WH(6), WL(6) };
  pk.d[7] = { Wn2 + 2 * MS, U(Wu2, 2), nullptr, nullptr, WH(7), WL(7) };
  pk.d[8] = { Ws2 + 0 * MS, L(Wu2, 0), Ws2 + 2 * MS, L(Wu2, 2), WH(8), WL(8) };
  pk.d[9] = { Ws2 + 1 * MS, L(Wu2, 1), nullptr, nullptr, WH(9), WL(9) };

  const int gdrop = (int)((nh / 2 + 255) / 256);
  const int gE    = (E + 255) / 256;
  const int gmm   = (n + 127) / 128;
  const int gga1  = (n * 64 + 255) / 256;
  const int gga2  = (2 * n * 64 + 255) / 256;
  const int nbA   = (n3 + 1023) / 1024;

  // ---- CSR build ----
  hipMemsetAsync(cnt, 0, (size_t)n3 * sizeof(int), stream);
  k_count3<<<3 * gE, 256, 0, stream>>>(ei0, ei1, ei2, cnt, E, n, gE);
  k_scanA<<<nbA, 256, 0, stream>>>(cnt, off, bsum, n3);
  k_scanB<<<1, 256, 0, stream>>>(bsum, nbA, off, n3);
  k_scanC<<<(n3 + 255) / 256, 256, 0, stream>>>(off, bsum, cur, n3);
  k_fill3<<<3 * gE, 256, 0, stream>>>(ei0, ei1, ei2, cur, srcl, E, n, gE);

  // ---- weights / biases ----
  k_wprec<<<40, 256, 0, stream>>>(pk);
  k_bias<<<1, 256, 0, stream>>>(bn1, bs1, bu1, Wu1, cbA1, cbB1);
  k_bias<<<1, 256, 0, stream>>>(bn2, bs2, bu2, Wu2, cbA2, cbB2);

  // ---- input dropout+relu -> interleaved ----
  k_drop_in<<<gdrop, 256, 0, stream>>>(xA, buf_hA, (int)(nh / 2), dk[0][0], dk[0][1]);
  k_drop_in<<<gdrop, 256, 0, stream>>>(xB, buf_hB, (int)(nh / 2), dk[1][0], dk[1][1]);

  // ---- layer 1 ----
  k_gather2<<<gga2, 256, 0, stream>>>(buf_hA, off + n, g1,
                                      buf_hB, off + 2 * n, g2, srcl, n);  // ei1, ei2
  k_mmx<2, 1><<<gmm, 256, 0, stream>>>(g1, buf_hB, nullptr,
                                       WH(1), WL(1), WH(4), WL(4), nullptr, nullptr,
                                       cbB1, buf_hB, n, dk[3][0], dk[3][1]);  // h2B in place
  k_gather1<<<gga1, 256, 0, stream>>>(buf_hA, off, g1, srcl, n);              // ei0
  k_mmx<3, 1><<<gmm, 256, 0, stream>>>(g1, g2, buf_hA,
                                       WH(0), WL(0), WH(2), WL(2), WH(3), WL(3),
                                       cbA1, buf_hA, n, dk[2][0], dk[2][1]);  // h2A in place

  // ---- layer 2 ----
  float* oA = (float*)d_out;
  float* oB = oA + nh;
  k_gather2<<<gga2, 256, 0, stream>>>(buf_hA, off + n, g1,
                                      buf_hB, off + 2 * n, g2, srcl, n);  // ei1, ei2
  k_mmx<2, 0><<<gmm, 256, 0, stream>>>(g1, buf_hB, nullptr,
                                       WH(6), WL(6), WH(9), WL(9), nullptr, nullptr,
                                       cbB2, oB, n, 0u, 0u);
  k_gather1<<<gga1, 256, 0, stream>>>(buf_hA, off, g1, srcl, n);          // ei0
  k_mmx<3, 0><<<gmm, 256, 0, stream>>>(g1, g2, buf_hA,
                                       WH(5), WL(5), WH(7), WL(7), WH(8), WL(8),
                                       cbA2, oA, n, 0u, 0u);
}

// Round 6
// 1205.078 us; speedup vs baseline: 1.4309x; 1.4309x over previous
//
#include <hip/hip_runtime.h>
#include <cstdint>
#include <cstdio>

#define DIMF 128
#define BKT_SHIFT 9        // 512 dsts per bucket
#define BKT_MAX 1024       // supports n3 <= 524288
#define P1_CHUNK 8192      // edges per p1/bcount block
#define P2_CAP 12288       // LDS image capacity (mean bucket ~8192, sigma ~90)

typedef __attribute__((ext_vector_type(8))) short short8v;
typedef __attribute__((ext_vector_type(4))) float f32x4;

// Feature format: each row = 128 u32 words; word j = hi_bf16(x_j) | lo_bf16 << 16.

// ---------------- JAX threefry2x32 (exact) ----------------
__host__ __device__ __forceinline__ void tf2x32(uint32_t k0, uint32_t k1,
                                                uint32_t x0, uint32_t x1,
                                                uint32_t& o0, uint32_t& o1) {
  uint32_t ks2 = k0 ^ k1 ^ 0x1BD11BDAu;
  x0 += k0; x1 += k1;
#define TFR(r) { x0 += x1; x1 = (x1 << (r)) | (x1 >> (32 - (r))); x1 ^= x0; }
  TFR(13) TFR(15) TFR(26) TFR(6)
  x0 += k1;  x1 += ks2 + 1u;
  TFR(17) TFR(29) TFR(16) TFR(24)
  x0 += ks2; x1 += k0 + 2u;
  TFR(13) TFR(15) TFR(26) TFR(6)
  x0 += k0;  x1 += k1 + 3u;
  TFR(17) TFR(29) TFR(16) TFR(24)
  x0 += k1;  x1 += ks2 + 4u;
  TFR(13) TFR(15) TFR(26) TFR(6)
  x0 += ks2; x1 += k0 + 5u;
#undef TFR
  o0 = x0; o1 = x1;
}

__device__ __forceinline__ short f2bf_rne(float x) {
  uint32_t u = __float_as_uint(x);
  uint32_t r = (u + 0x7FFFu + ((u >> 16) & 1u)) >> 16;
  return (short)r;
}
__device__ __forceinline__ float bfhi_f(short h) {
  return __uint_as_float(((uint32_t)(uint16_t)h) << 16);
}
__device__ __forceinline__ uint32_t pack_hl(float v) {
  short hi = f2bf_rne(v);
  short lo = f2bf_rne(v - bfhi_f(hi));
  return (uint32_t)(uint16_t)hi | ((uint32_t)(uint16_t)lo << 16);
}
__device__ __forceinline__ float unpk_sum(uint32_t w) {
  return __uint_as_float(w << 16) + __uint_as_float(w & 0xFFFF0000u);
}
__device__ __forceinline__ void pack2(uint32_t we, uint32_t wo, uint32_t& h, uint32_t& l) {
  h = (we & 0xFFFFu) | (wo << 16);
  l = (we >> 16) | (wo & 0xFFFF0000u);
}

// ---------------- input dropout(0.2)+relu -> interleaved rows ----------------
__global__ __launch_bounds__(256) void k_drop_in(const float* __restrict__ in,
                                                 uint32_t* __restrict__ out,
                                                 int npair, uint32_t k0, uint32_t k1) {
  int p = blockIdx.x * 256 + threadIdx.x;
  if (p >= npair) return;
  int row = p >> 6, c2 = (p & 63) * 2;
  float2 x = *(const float2*)(in + (size_t)row * 128 + c2);
  uint32_t idx = (uint32_t)(row * 128 + c2);
  float v[2] = {x.x, x.y};
  uint32_t wv[2];
#pragma unroll
  for (int q = 0; q < 2; ++q) {
    uint32_t o0, o1;
    tf2x32(k0, k1, 0u, idx + q, o0, o1);
    uint32_t bits = o0 ^ o1;
    float u = __uint_as_float((bits >> 9) | 0x3f800000u) - 1.0f;
    float y = (u < 0.8f) ? (v[q] / 0.8f) : 0.0f;
    y = fmaxf(y, 0.0f);
    wv[q] = pack_hl(y);
  }
  *(uint2*)(out + (size_t)row * 128 + c2) = make_uint2(wv[0], wv[1]);
}

// ---------------- CSR build: 2-level bucket sort ----------------
// buckets of 512 consecutive unified dsts; bucket regions are final srcl regions.

__global__ __launch_bounds__(256) void k_bcount(const int* __restrict__ ei0,
                                                const int* __restrict__ ei1,
                                                const int* __restrict__ ei2,
                                                int* __restrict__ bcnt,
                                                int E, int n, int gE8, int nbk) {
  __shared__ int hist[BKT_MAX];
  int t = threadIdx.x;
  int type = blockIdx.x / gE8;
  int chunk = blockIdx.x - type * gE8;
  const int* ei = type == 0 ? ei0 : (type == 1 ? ei1 : ei2);
  int base = chunk * P1_CHUNK;
  int dof = type * n;
  for (int i = t; i < nbk; i += 256) hist[i] = 0;
  __syncthreads();
  for (int j = 0; j < P1_CHUNK / 256; ++j) {
    int e = base + j * 256 + t;
    if (e < E) atomicAdd(&hist[(ei[E + e] + dof) >> BKT_SHIFT], 1);
  }
  __syncthreads();
  for (int i = t; i < nbk; i += 256)
    if (hist[i]) atomicAdd(&bcnt[i], hist[i]);
}

__global__ __launch_bounds__(256) void k_bscan(const int* __restrict__ bcnt,
                                               int* __restrict__ boff,
                                               int* __restrict__ gcur,
                                               int* __restrict__ off,
                                               int nbk, int n3) {
  __shared__ int ts[256];
  int t = threadIdx.x;
  int base = t * 4;
  int v[4];
#pragma unroll
  for (int i = 0; i < 4; ++i) v[i] = (base + i < nbk) ? bcnt[base + i] : 0;
  ts[t] = v[0] + v[1] + v[2] + v[3];
  __syncthreads();
  for (int ofs = 1; ofs < 256; ofs <<= 1) {
    int x = ts[t];
    int y = (t >= ofs) ? ts[t - ofs] : 0;
    __syncthreads();
    ts[t] = x + y;
    __syncthreads();
  }
  int run = (t == 0) ? 0 : ts[t - 1];
#pragma unroll
  for (int i = 0; i < 4; ++i) {
    if (base + i < nbk) { boff[base + i] = run; gcur[base + i] = run; }
    run += v[i];
  }
  if (t == 255) { boff[nbk] = ts[255]; off[n3] = ts[255]; }
}

// phase 1: scatter packed (src | localdst<<20) into per-block private runs
__global__ __launch_bounds__(256) void k_p1(const int* __restrict__ ei0,
                                            const int* __restrict__ ei1,
                                            const int* __restrict__ ei2,
                                            int* __restrict__ gcur,
                                            uint32_t* __restrict__ p1o,
                                            int E, int n, int gE8, int nbk) {
  __shared__ int hist[BKT_MAX];
  __shared__ int cur[BKT_MAX];
  int t = threadIdx.x;
  int type = blockIdx.x / gE8;
  int chunk = blockIdx.x - type * gE8;
  const int* ei = type == 0 ? ei0 : (type == 1 ? ei1 : ei2);
  int base = chunk * P1_CHUNK;
  int dof = type * n;
  for (int i = t; i < nbk; i += 256) hist[i] = 0;
  __syncthreads();
  int sv[P1_CHUNK / 256];
  int dv[P1_CHUNK / 256];
#pragma unroll
  for (int j = 0; j < P1_CHUNK / 256; ++j) {
    int e = base + j * 256 + t;
    if (e < E) { sv[j] = ei[e]; dv[j] = ei[E + e] + dof; }
    else dv[j] = -1;
  }
#pragma unroll
  for (int j = 0; j < P1_CHUNK / 256; ++j)
    if (dv[j] >= 0) atomicAdd(&hist[dv[j] >> BKT_SHIFT], 1);
  __syncthreads();
  for (int i = t; i < nbk; i += 256) {
    int h = hist[i];
    if (h > 0) cur[i] = atomicAdd(&gcur[i], h);
  }
  __syncthreads();
#pragma unroll
  for (int j = 0; j < P1_CHUNK / 256; ++j) {
    if (dv[j] >= 0) {
      int bkt = dv[j] >> BKT_SHIFT;
      int pos = atomicAdd(&cur[bkt], 1);
      p1o[pos] = (uint32_t)sv[j] | ((uint32_t)(dv[j] & 511) << 20);
    }
  }
}

// phase 2: counting sort within bucket (LDS), write off[] + coalesced srcl
__global__ __launch_bounds__(256) void k_p2(const uint32_t* __restrict__ p1o,
                                            const int* __restrict__ boff,
                                            int* __restrict__ off,
                                            int* __restrict__ srcl, int n3) {
  __shared__ int cnt_l[512];
  __shared__ int off_l[512];
  __shared__ int cur_l[512];
  __shared__ int ts[256];
  __shared__ int img[P2_CAP];
  int b = blockIdx.x;
  int t = threadIdx.x;
  int rb = boff[b], re = boff[b + 1];
  int sz = re - rb;
  int d0 = b << BKT_SHIFT;
  cnt_l[t] = 0; cnt_l[t + 256] = 0;
  __syncthreads();
  for (int i = rb + t; i < re; i += 256)
    atomicAdd(&cnt_l[p1o[i] >> 20], 1);
  __syncthreads();
  int c0 = cnt_l[2 * t], c1 = cnt_l[2 * t + 1];
  ts[t] = c0 + c1;
  __syncthreads();
  for (int ofs = 1; ofs < 256; ofs <<= 1) {
    int x = ts[t];
    int y = (t >= ofs) ? ts[t - ofs] : 0;
    __syncthreads();
    ts[t] = x + y;
    __syncthreads();
  }
  int ebase = (t == 0) ? 0 : ts[t - 1];
  off_l[2 * t] = ebase; off_l[2 * t + 1] = ebase + c0;
  cur_l[2 * t] = ebase; cur_l[2 * t + 1] = ebase + c0;
  __syncthreads();
  for (int j = t; j < 512; j += 256) {
    int d = d0 + j;
    if (d < n3) off[d] = rb + off_l[j];
  }
  if (sz <= P2_CAP) {
    for (int i = rb + t; i < re; i += 256) {
      uint32_t w = p1o[i];
      int pos = atomicAdd(&cur_l[w >> 20], 1);
      img[pos] = (int)(w & 0xFFFFFu);
    }
    __syncthreads();
    for (int i = t; i < sz; i += 256) srcl[rb + i] = img[i];
  } else {  // fallback (statistically unreachable for uniform-random dst)
    for (int i = rb + t; i < re; i += 256) {
      uint32_t w = p1o[i];
      int pos = atomicAdd(&cur_l[w >> 20], 1);
      srcl[rb + pos] = (int)(w & 0xFFFFFu);
    }
  }
}

// ---------------- CSR gather-mean (interleaved in/out) ----------------
__device__ __forceinline__ void gather_one(const uint32_t* __restrict__ feat,
                                           const int* __restrict__ off,
                                           const int* __restrict__ srcl,
                                           uint32_t* __restrict__ out,
                                           int d, int lane) {
  int b = off[d], e = off[d + 1];
  float a0 = 0.f, a1 = 0.f, b0 = 0.f, b1 = 0.f;
  float c0 = 0.f, c1 = 0.f, d0 = 0.f, d1 = 0.f;
  const int c2 = lane * 2;
  int j = b;
  for (; j + 3 < e; j += 4) {
    int s0 = srcl[j], s1 = srcl[j + 1], s2 = srcl[j + 2], s3 = srcl[j + 3];
    uint2 w0 = *(const uint2*)(feat + (size_t)s0 * 128 + c2);
    uint2 w1 = *(const uint2*)(feat + (size_t)s1 * 128 + c2);
    uint2 w2 = *(const uint2*)(feat + (size_t)s2 * 128 + c2);
    uint2 w3 = *(const uint2*)(feat + (size_t)s3 * 128 + c2);
    a0 += unpk_sum(w0.x); a1 += unpk_sum(w0.y);
    b0 += unpk_sum(w1.x); b1 += unpk_sum(w1.y);
    c0 += unpk_sum(w2.x); c1 += unpk_sum(w2.y);
    d0 += unpk_sum(w3.x); d1 += unpk_sum(w3.y);
  }
  for (; j < e; ++j) {
    int s = srcl[j];
    uint2 w = *(const uint2*)(feat + (size_t)s * 128 + c2);
    a0 += unpk_sum(w.x); a1 += unpk_sum(w.y);
  }
  float sc = 1.0f / (float)max(e - b, 1);
  float v0 = ((a0 + b0) + (c0 + d0)) * sc;
  float v1 = ((a1 + b1) + (c1 + d1)) * sc;
  *(uint2*)(out + (size_t)d * 128 + c2) = make_uint2(pack_hl(v0), pack_hl(v1));
}

__global__ __launch_bounds__(256) void k_gather2(
    const uint32_t* __restrict__ fX, const int* __restrict__ offX, uint32_t* __restrict__ oX,
    const uint32_t* __restrict__ fY, const int* __restrict__ offY, uint32_t* __restrict__ oY,
    const int* __restrict__ srcl, int n) {
  int wid = (blockIdx.x * 256 + threadIdx.x) >> 6;
  int lane = threadIdx.x & 63;
  if (wid >= 2 * n) return;
  if (wid < n) gather_one(fX, offX, srcl, oX, wid, lane);
  else         gather_one(fY, offY, srcl, oY, wid - n, lane);
}

__global__ __launch_bounds__(256) void k_gather1(
    const uint32_t* __restrict__ f, const int* __restrict__ off, uint32_t* __restrict__ o,
    const int* __restrict__ srcl, int n) {
  int wid = (blockIdx.x * 256 + threadIdx.x) >> 6;
  int lane = threadIdx.x & 63;
  if (wid >= n) return;
  gather_one(f, off, srcl, o, wid, lane);
}

// ---------------- combined-weight precompute: C=A0@B0(+A1@B1) -> transposed hi/lo planar ----------------
struct WDesc { const float* A0; const float* B0; const float* A1; const float* B1; short* Ch; short* Cl; };
struct WPack { WDesc d[10]; };

__global__ __launch_bounds__(256) void k_wprec(WPack p) {
  const WDesc d = p.d[blockIdx.x >> 2];
  const int rt = blockIdx.x & 3;
  __shared__ float A_s[32 * 128];
  const int t = threadIdx.x;
  const int c = t & 127, rh = t >> 7;
  float acc[16];
#pragma unroll
  for (int i = 0; i < 16; ++i) acc[i] = 0.f;
  for (int pass = 0; pass < 2; ++pass) {
    const float* A = pass ? d.A1 : d.A0;
    const float* B = pass ? d.B1 : d.B0;
    if (!A) break;
    __syncthreads();
#pragma unroll
    for (int j = 0; j < 4; ++j) {
      int f = t + 256 * j;
      *(float4*)(A_s + 4 * f) = *(const float4*)(A + (size_t)rt * 32 * 128 + 4 * f);
    }
    __syncthreads();
    for (int k = 0; k < 128; ++k) {
      float b = B[(size_t)k * 128 + c];
#pragma unroll
      for (int i = 0; i < 16; ++i)
        acc[i] += A_s[(rh + 2 * i) * 128 + k] * b;
    }
  }
#pragma unroll
  for (int i = 0; i < 16; ++i) {
    int k = rt * 32 + rh + 2 * i;
    float v = acc[i];
    short hi = f2bf_rne(v);
    short lo = f2bf_rne(v - bfhi_f(hi));
    d.Ch[(size_t)c * 128 + k] = hi;
    d.Cl[(size_t)c * 128 + k] = lo;
  }
}

// ---------------- combined bias ----------------
__global__ __launch_bounds__(256) void k_bias(const float* __restrict__ bn,
                                              const float* __restrict__ bs,
                                              const float* __restrict__ bu,
                                              const float* __restrict__ Wu,
                                              float* __restrict__ cbA, float* __restrict__ cbB) {
  int t = threadIdx.x;
  int h = t & 127;
  if (t < 128) {
    float acc = bu[0 * 128 + h] + bu[2 * 128 + h];
    for (int j = 0; j < 128; ++j) {
      acc += bn[0 * 128 + j] * Wu[(size_t)0 * 32768 + (size_t)j * 128 + h];
      acc += bs[0 * 128 + j] * Wu[(size_t)0 * 32768 + 16384 + (size_t)j * 128 + h];
      acc += bn[2 * 128 + j] * Wu[(size_t)2 * 32768 + (size_t)j * 128 + h];
      acc += bs[2 * 128 + j] * Wu[(size_t)2 * 32768 + 16384 + (size_t)j * 128 + h];
    }
    cbA[h] = acc;
  } else {
    float acc = bu[128 + h];
    for (int j = 0; j < 128; ++j) {
      acc += bn[128 + j] * Wu[(size_t)1 * 32768 + (size_t)j * 128 + h];
      acc += bs[128 + j] * Wu[(size_t)1 * 32768 + 16384 + (size_t)j * 128 + h];
    }
    cbB[h] = acc;
  }
}

// ---------------- split-bf16 MFMA multi-term matmul (interleaved features) ----------------
template <int NT, int MODE>
__global__ __launch_bounds__(256, 2) void k_mmx(
    const uint32_t* __restrict__ s0, const uint32_t* __restrict__ s1, const uint32_t* __restrict__ s2,
    const short* __restrict__ w0h, const short* __restrict__ w0l,
    const short* __restrict__ w1h, const short* __restrict__ w1l,
    const short* __restrict__ w2h, const short* __restrict__ w2l,
    const float* __restrict__ bias, void* __restrict__ outv, int n,
    uint32_t k0, uint32_t k1) {
  __shared__ short A_s[128 * 72];   // [row][32hi|32lo|8pad] shorts, 144B stride
  __shared__ short W_s[128 * 72];   // [n][32hi|32lo|8pad]
  const int t = threadIdx.x;
  const int r0 = blockIdx.x * 128;
  const int lane = t & 63;
  const int w = t >> 6;
  const int wr = w >> 1, wc = w & 1;
  const int lr = lane & 15, lg = lane >> 4;
  const int sr = t >> 1, sh = t & 1;

  f32x4 acc[4][4];
#pragma unroll
  for (int nf = 0; nf < 4; ++nf) {
    float bv = bias[wc * 64 + nf * 16 + lr];
#pragma unroll
    for (int mf = 0; mf < 4; ++mf) acc[mf][nf] = {bv, bv, bv, bv};
  }

  for (int term = 0; term < NT; ++term) {
    const uint32_t* src = term == 0 ? s0 : (term == 1 ? s1 : s2);
    const short* wh  = term == 0 ? w0h : (term == 1 ? w1h : w2h);
    const short* wl  = term == 0 ? w0l : (term == 1 ? w1l : w2l);
    const short* wsrc = sh ? wl : wh;
    for (int ks = 0; ks < 4; ++ks) {
      __syncthreads();
      { // A tile: 16 interleaved words -> 16 hi + 16 lo shorts (planar)
        const uint4* ga = (const uint4*)(src + (size_t)(r0 + sr) * 128 + ks * 32 + sh * 16);
        uint4 q0 = ga[0], q1 = ga[1], q2 = ga[2], q3 = ga[3];
        uint32_t h[8], l[8];
        pack2(q0.x, q0.y, h[0], l[0]); pack2(q0.z, q0.w, h[1], l[1]);
        pack2(q1.x, q1.y, h[2], l[2]); pack2(q1.z, q1.w, h[3], l[3]);
        pack2(q2.x, q2.y, h[4], l[4]); pack2(q2.z, q2.w, h[5], l[5]);
        pack2(q3.x, q3.y, h[6], l[6]); pack2(q3.z, q3.w, h[7], l[7]);
        uint4* Ah = (uint4*)(A_s + sr * 72 + sh * 16);
        uint4* Al = (uint4*)(A_s + sr * 72 + 32 + sh * 16);
        Ah[0] = make_uint4(h[0], h[1], h[2], h[3]);
        Ah[1] = make_uint4(h[4], h[5], h[6], h[7]);
        Al[0] = make_uint4(l[0], l[1], l[2], l[3]);
        Al[1] = make_uint4(l[4], l[5], l[6], l[7]);
        const uint4* gw = (const uint4*)(wsrc + sr * 128 + ks * 32);
        uint4 b0 = gw[0], b1 = gw[1], b2 = gw[2], b3 = gw[3];
        uint4* lw = (uint4*)(W_s + sr * 72 + sh * 32);
        lw[0] = b0; lw[1] = b1; lw[2] = b2; lw[3] = b3;
      }
      __syncthreads();
      short8v whi[4], wlo[4];
#pragma unroll
      for (int nf = 0; nf < 4; ++nf) {
        int nc = wc * 64 + nf * 16 + lr;
        whi[nf] = *(const short8v*)(W_s + nc * 72 + lg * 8);
        wlo[nf] = *(const short8v*)(W_s + nc * 72 + 32 + lg * 8);
      }
#pragma unroll
      for (int mf = 0; mf < 4; ++mf) {
        int ar = wr * 64 + mf * 16 + lr;
        short8v ah = *(const short8v*)(A_s + ar * 72 + lg * 8);
        short8v al = *(const short8v*)(A_s + ar * 72 + 32 + lg * 8);
#pragma unroll
        for (int nf = 0; nf < 4; ++nf) {
          acc[mf][nf] = __builtin_amdgcn_mfma_f32_16x16x32_bf16(ah, whi[nf], acc[mf][nf], 0, 0, 0);
          acc[mf][nf] = __builtin_amdgcn_mfma_f32_16x16x32_bf16(ah, wlo[nf], acc[mf][nf], 0, 0, 0);
          acc[mf][nf] = __builtin_amdgcn_mfma_f32_16x16x32_bf16(al, whi[nf], acc[mf][nf], 0, 0, 0);
        }
      }
    }
  }

#pragma unroll
  for (int mf = 0; mf < 4; ++mf) {
#pragma unroll
    for (int r = 0; r < 4; ++r) {
      int g = r0 + wr * 64 + mf * 16 + lg * 4 + r;
      if (g >= n) continue;
#pragma unroll
      for (int nf = 0; nf < 4; ++nf) {
        int col = wc * 64 + nf * 16 + lr;
        float v = acc[mf][nf][r];
        if constexpr (MODE == 1) {
          uint32_t o0, o1;
          tf2x32(k0, k1, 0u, (uint32_t)(g * 128 + col), o0, o1);
          uint32_t bits = o0 ^ o1;
          float u = __uint_as_float((bits >> 9) | 0x3f800000u) - 1.0f;
          v = (u < 0.8f) ? (v / 0.8f) : 0.0f;
          v = fmaxf(v, 0.0f);
          ((uint32_t*)outv)[(size_t)g * 128 + col] = pack_hl(v);
        } else {
          ((float*)outv)[(size_t)g * 128 + col] = v;
        }
      }
    }
  }
}

// ---------------- host driver ----------------
extern "C" void kernel_launch(void* const* d_in, const int* in_sizes, int n_in,
                              void* d_out, int out_size, void* d_ws, size_t ws_size,
                              hipStream_t stream) {
  const float* xA  = (const float*)d_in[0];
  const float* xB  = (const float*)d_in[1];
  const int*   ei0 = (const int*)d_in[2];
  const int*   ei1 = (const int*)d_in[3];
  const int*   ei2 = (const int*)d_in[4];
  const float* Wn1 = (const float*)d_in[5];
  const float* Ws1 = (const float*)d_in[6];
  const float* Wu1 = (const float*)d_in[7];
  const float* Wn2 = (const float*)d_in[8];
  const float* Ws2 = (const float*)d_in[9];
  const float* Wu2 = (const float*)d_in[10];
  const float* bn1 = (const float*)d_in[11];
  const float* bs1 = (const float*)d_in[12];
  const float* bu1 = (const float*)d_in[13];
  const float* bn2 = (const float*)d_in[14];
  const float* bs2 = (const float*)d_in[15];
  const float* bu2 = (const float*)d_in[16];

  const int n  = in_sizes[0] / DIMF;        // 100000
  const int E  = in_sizes[2] / 2;           // 1600000
  const int n3 = 3 * n;
  const int nbk = (n3 + 511) >> BKT_SHIFT;  // 586
  const size_t nh = (size_t)n * DIMF;

  float* ws = (float*)d_ws;
  uint32_t* buf_hA = (uint32_t*)(ws);           // hA -> h2A (in place)
  uint32_t* buf_hB = (uint32_t*)(ws + nh);      // hB -> h2B (in place)
  uint32_t* g1     = (uint32_t*)(ws + 2 * nh);  // gather scratch / p1o alias
  uint32_t* g2     = (uint32_t*)(ws + 3 * nh);  // gather scratch
  short* wtsS   = (short*)(ws + 4 * nh);        // 10 x (16384 hi + 16384 lo) shorts
  float* biasF  = (float*)(wtsS + 10 * 32768);
  float* cbA1 = biasF, *cbB1 = biasF + 128, *cbA2 = biasF + 256, *cbB2 = biasF + 384;
  int* off  = (int*)(biasF + 512);          // [n3+1]
  int* bcnt = off + n3 + 1;                 // [BKT_MAX]
  int* boff = bcnt + BKT_MAX;               // [BKT_MAX+1]
  int* gcur = boff + BKT_MAX + 1;           // [BKT_MAX]
  int* srcl = gcur + BKT_MAX;               // [3E]
  uint32_t* p1o = g1;                        // 3E u32, used only before gathers

  size_t need_bytes = (4 * nh + 512) * sizeof(float)
                    + (size_t)10 * 32768 * sizeof(short)
                    + ((size_t)n3 + 1 + 3 * BKT_MAX + 1 + (size_t)3 * E) * sizeof(int)
                    + 65536;
  if (ws_size < need_bytes) {
    fprintf(stderr, "kernel_launch: ws too small (%zu < %zu)\n", ws_size, need_bytes);
    return;
  }

  // JAX keys: dk = split(key(42), 4) (partitionable threefry, verified round 2)
  uint32_t dk[4][2];
  for (uint32_t i = 0; i < 4; ++i) tf2x32(0u, 42u, 0u, i, dk[i][0], dk[i][1]);

  WPack pk;
  auto U = [](const float* Wu, int t) { return Wu + (size_t)t * 32768; };
  auto L = [](const float* Wu, int t) { return Wu + (size_t)t * 32768 + 16384; };
  auto WH = [&](int m) { return wtsS + (size_t)m * 32768; };
  auto WL = [&](int m) { return wtsS + (size_t)m * 32768 + 16384; };
  const size_t MS = 128 * 128;
  pk.d[0] = { Wn1 + 0 * MS, U(Wu1, 0), nullptr, nullptr, WH(0), WL(0) };
  pk.d[1] = { Wn1 + 1 * MS, U(Wu1, 1), nullptr, nullptr, WH(1), WL(1) };
  pk.d[2] = { Wn1 + 2 * MS, U(Wu1, 2), nullptr, nullptr, WH(2), WL(2) };
  pk.d[3] = { Ws1 + 0 * MS, L(Wu1, 0), Ws1 + 2 * MS, L(Wu1, 2), WH(3), WL(3) };
  pk.d[4] = { Ws1 + 1 * MS, L(Wu1, 1), nullptr, nullptr, WH(4), WL(4) };
  pk.d[5] = { Wn2 + 0 * MS, U(Wu2, 0), nullptr, nullptr, WH(5), WL(5) };
  pk.d[6] = { Wn2 + 1 * MS, U(Wu2, 1), nullptr, nullptr, WH(6), WL(6) };
  pk.d[7] = { Wn2 + 2 * MS, U(Wu2, 2), nullptr, nullptr, WH(7), WL(7) };
  pk.d[8] = { Ws2 + 0 * MS, L(Wu2, 0), Ws2 + 2 * MS, L(Wu2, 2), WH(8), WL(8) };
  pk.d[9] = { Ws2 + 1 * MS, L(Wu2, 1), nullptr, nullptr, WH(9), WL(9) };

  const int gdrop = (int)((nh / 2 + 255) / 256);
  const int gE8   = (E + P1_CHUNK - 1) / P1_CHUNK;
  const int gmm   = (n + 127) / 128;
  const int gga1  = (n * 64 + 255) / 256;
  const int gga2  = (2 * n * 64 + 255) / 256;

  // ---- CSR build: 2-level bucket sort ----
  hipMemsetAsync(bcnt, 0, (size_t)nbk * sizeof(int), stream);
  k_bcount<<<3 * gE8, 256, 0, stream>>>(ei0, ei1, ei2, bcnt, E, n, gE8, nbk);
  k_bscan<<<1, 256, 0, stream>>>(bcnt, boff, gcur, off, nbk, n3);
  k_p1<<<3 * gE8, 256, 0, stream>>>(ei0, ei1, ei2, gcur, p1o, E, n, gE8, nbk);
  k_p2<<<nbk, 256, 0, stream>>>(p1o, boff, off, srcl, n3);

  // ---- weights / biases ----
  k_wprec<<<40, 256, 0, stream>>>(pk);
  k_bias<<<1, 256, 0, stream>>>(bn1, bs1, bu1, Wu1, cbA1, cbB1);
  k_bias<<<1, 256, 0, stream>>>(bn2, bs2, bu2, Wu2, cbA2, cbB2);

  // ---- input dropout+relu -> interleaved ----
  k_drop_in<<<gdrop, 256, 0, stream>>>(xA, buf_hA, (int)(nh / 2), dk[0][0], dk[0][1]);
  k_drop_in<<<gdrop, 256, 0, stream>>>(xB, buf_hB, (int)(nh / 2), dk[1][0], dk[1][1]);

  // ---- layer 1 ----
  k_gather2<<<gga2, 256, 0, stream>>>(buf_hA, off + n, g1,
                                      buf_hB, off + 2 * n, g2, srcl, n);  // ei1, ei2
  k_mmx<2, 1><<<gmm, 256, 0, stream>>>(g1, buf_hB, nullptr,
                                       WH(1), WL(1), WH(4), WL(4), nullptr, nullptr,
                                       cbB1, buf_hB, n, dk[3][0], dk[3][1]);  // h2B in place
  k_gather1<<<gga1, 256, 0, stream>>>(buf_hA, off, g1, srcl, n);              // ei0
  k_mmx<3, 1><<<gmm, 256, 0, stream>>>(g1, g2, buf_hA,
                                       WH(0), WL(0), WH(2), WL(2), WH(3), WL(3),
                                       cbA1, buf_hA, n, dk[2][0], dk[2][1]);  // h2A in place

  // ---- layer 2 ----
  float* oA = (float*)d_out;
  float* oB = oA + nh;
  k_gather2<<<gga2, 256, 0, stream>>>(buf_hA, off + n, g1,
                                      buf_hB, off + 2 * n, g2, srcl, n);  // ei1, ei2
  k_mmx<2, 0><<<gmm, 256, 0, stream>>>(g1, buf_hB, nullptr,
                                       WH(6), WL(6), WH(9), WL(9), nullptr, nullptr,
                                       cbB2, oB, n, 0u, 0u);
  k_gather1<<<gga1, 256, 0, stream>>>(buf_hA, off, g1, srcl, n);          // ei0
  k_mmx<3, 0><<<gmm, 256, 0, stream>>>(g1, g2, buf_hA,
                                       WH(5), WL(5), WH(7), WL(7), WH(8), WL(8),
                                       cbA2, oA, n, 0u, 0u);
}